// Round 2
// baseline (129128.687 us; speedup 1.0000x reference)
//
#include <hip/hip_runtime.h>
#include <stdint.h>

// VanillaRNN — Round 11: work-reshape to kill same-address stream contention.
//
// R10 post-mortem (FAILED 84 ms): global_load_lds staging TRIPLED HBM traffic
// (WRITE_SIZE 15.8->75.5 GB: LDS-DMA fill counted as TCC writes; FETCH 2x).
// Reverted entirely.
//
// R9 diagnosis refined: dur == traffic/877GB/s at 11% HBM BW with W (1.31 MB)
// L2-fitting => NOT a BW roofline. 128 WGs stream the SAME W addresses in
// lockstep -> single L3-slice/L2-set hotspot -> ~3000 cyc effective latency
// per 16-row group, with only 16x4B loads in flight per wave.
//
// R11 reshape: thread owns 4 columns (dwordx4 W loads = 4x bytes/slot, 4x
// fewer load insts) x 2 batch items; WG = 128 col-threads x 4 batch-groups
// = 8 batch items -> grid 32 (4 WGs/XCD, 4x fewer W streams; intra-WG 4x
// reuse served by L1). Explicit ping-pong register double-buffer (1 group
// ahead, wraps across the step barrier) keeps 8 dwordx4 in flight.
//
// Numerics BIT-IDENTICAL to R9 (passed, absmax 0.125): per column j the
// frozen ascending fmaf chains, contract(off), Eigen tanh, f64 head. Only
// the assignment of columns/batches to lanes changed (independent chains).

#define BATCH   256
#define SEQ     1024
#define IN_DIM  128
#define HIDDEN  512
#define CLASSES 128
#define BPW     8               // batch items per WG
#define NWG     (BATCH / BPW)   // 32

// ---- Eigen/XLA rational tanh f32, FMA variant — verbatim R5 ----
__device__ __forceinline__ float eigen_tanhf_fma(float ax) {
#pragma clang fp contract(off)
    const float pc = 7.99881172180175781f, mc = -7.99881172180175781f;
    float x = fmaxf(fminf(ax, pc), mc);
    float x2 = x * x;
    float p = __builtin_fmaf(x2, -2.76076847742355e-16f, 2.00018790482477e-13f);
    p = __builtin_fmaf(x2, p, -8.60467152213735e-11f);
    p = __builtin_fmaf(x2, p, 5.12229709037114e-08f);
    p = __builtin_fmaf(x2, p, 1.48572235717979e-05f);
    p = __builtin_fmaf(x2, p, 6.37261928875436e-04f);
    p = __builtin_fmaf(x2, p, 4.89352455891786e-03f);
    p = x * p;
    float q = __builtin_fmaf(x2, 1.19825839466702e-06f, 1.18534705686654e-04f);
    q = __builtin_fmaf(x2, q, 2.26843463243900e-03f);
    q = __builtin_fmaf(x2, q, 4.89352518554385e-03f);
    float r = p / q;
    return (fabsf(ax) < 0.0004f) ? ax : r;
}

struct W8 { float4 w[8]; };

// load 8 consecutive W rows of this thread's 4-column slice (8 x dwordx4)
__device__ __forceinline__ void loadW8(const float* __restrict__ col, int row0, W8& d) {
#pragma unroll
    for (int r = 0; r < 8; ++r)
        d.w[r] = *(const float4*)(col + (size_t)(row0 + r) * HIDDEN);
}

// consume 8 rows: state at hb is [row][2] interleaved, float4 = rows r,r+1
// x b0,b1. Per-accumulator chain order = ascending rows (frozen, == R9).
__device__ __forceinline__ void fma8(const W8& W,
                                     const float* __restrict__ hb,
                                     float (&s0)[4], float (&s1)[4]) {
#pragma clang fp contract(off)
    const float4 p0 = *(const float4*)(hb + 0);
    const float4 p1 = *(const float4*)(hb + 4);
    const float4 p2 = *(const float4*)(hb + 8);
    const float4 p3 = *(const float4*)(hb + 12);
#pragma unroll
    for (int e = 0; e < 4; ++e) {
        const float4 pe = (e == 0) ? p0 : (e == 1) ? p1 : (e == 2) ? p2 : p3;
        const float4 wlo = W.w[2 * e];
        const float4 whi = W.w[2 * e + 1];
        s0[0] = __builtin_fmaf(pe.x, wlo.x, s0[0]); s1[0] = __builtin_fmaf(pe.y, wlo.x, s1[0]);
        s0[1] = __builtin_fmaf(pe.x, wlo.y, s0[1]); s1[1] = __builtin_fmaf(pe.y, wlo.y, s1[1]);
        s0[2] = __builtin_fmaf(pe.x, wlo.z, s0[2]); s1[2] = __builtin_fmaf(pe.y, wlo.z, s1[2]);
        s0[3] = __builtin_fmaf(pe.x, wlo.w, s0[3]); s1[3] = __builtin_fmaf(pe.y, wlo.w, s1[3]);
        s0[0] = __builtin_fmaf(pe.z, whi.x, s0[0]); s1[0] = __builtin_fmaf(pe.w, whi.x, s1[0]);
        s0[1] = __builtin_fmaf(pe.z, whi.y, s0[1]); s1[1] = __builtin_fmaf(pe.w, whi.y, s1[1]);
        s0[2] = __builtin_fmaf(pe.z, whi.z, s0[2]); s1[2] = __builtin_fmaf(pe.w, whi.z, s1[2]);
        s0[3] = __builtin_fmaf(pe.z, whi.w, s0[3]); s1[3] = __builtin_fmaf(pe.w, whi.w, s1[3]);
    }
}

__global__ __launch_bounds__(512, 2)
void rnn_fast(const float* __restrict__ x,
              const float* __restrict__ W_hh,
              const float* __restrict__ W_xh,
              const float* __restrict__ W_hy,
              const float* __restrict__ b_h,
              const float* __restrict__ b_y,
              float* __restrict__ out)
{
    // state: [buf][batch-group][row][2]  (interleaved pair, R9-style)
    __shared__ alignas(16) float hti[2][4][HIDDEN][2];   // 32 KB
    __shared__ alignas(16) float xti[2][4][IN_DIM][2];   //  8 KB

    const int j   = threadIdx.x;
    const int g   = blockIdx.x;
    const int cg  = j & 127;     // column group: columns 4cg..4cg+3
    const int bgp = j >> 7;      // batch pair 0..3 within WG
    const int c0  = 4 * cg;

    const float* colX = W_xh + c0;
    const float* colH = W_hh + c0;
    const float4 bq = *(const float4*)(b_h + c0);
    const float bhv[4] = {bq.x, bq.y, bq.z, bq.w};

    // this thread's x element stream: element k==cg of batch items 2bgp,2bgp+1
    const float* px0 = x + (size_t)(BPW * g + 2 * bgp) * SEQ * IN_DIM + cg;
    const float* px1 = px0 + (size_t)SEQ * IN_DIM;

    // init h=0 and x_0
#pragma unroll
    for (int cc = 0; cc < 4; ++cc)
        *(float2*)&hti[0][bgp][c0 + cc][0] = make_float2(0.0f, 0.0f);
    *(float2*)&xti[0][bgp][cg][0] = make_float2(px0[0], px1[0]);
    __syncthreads();

    W8 w0, w1;
    loadW8(colX, 0, w0);   // steady-state invariant: w0 = xh rows 0..7

    for (int t = 0; t < SEQ; ++t) {
        const int cur = t & 1, nxt = cur ^ 1;
        const float* xb = &xti[cur][bgp][0][0];
        const float* hb = &hti[cur][bgp][0][0];

        // ---- xh: 16 groups of 8 rows, 1-group-ahead ping-pong ----
        float a0[4] = {0, 0, 0, 0}, a1[4] = {0, 0, 0, 0};
        for (int q = 0; q < 16; q += 2) {
            loadW8(colX, 8 * (q + 1), w1);
            fma8(w0, xb + 16 * q, a0, a1);
            if (q + 2 < 16) loadW8(colX, 8 * (q + 2), w0);
            else            loadW8(colH, 0, w0);          // seed hh
            fma8(w1, xb + 16 * (q + 1), a0, a1);
        }
        {
#pragma clang fp contract(off)
#pragma unroll
            for (int cc = 0; cc < 4; ++cc) {
                a0[cc] = a0[cc] + bhv[cc];
                a1[cc] = a1[cc] + bhv[cc];
            }
        }

        // x_{t+1} loads issued here; LDS store deferred past the hh loop
        const bool morex = (t + 1 < SEQ);
        float xp0 = 0.0f, xp1 = 0.0f;
        if (morex) {
            xp0 = px0[(size_t)(t + 1) * IN_DIM];
            xp1 = px1[(size_t)(t + 1) * IN_DIM];
        }

        // ---- hh: 64 groups of 8 rows; last prefetch wraps to next step ----
        float m0[4] = {0, 0, 0, 0}, m1[4] = {0, 0, 0, 0};
        for (int q = 0; q < 64; q += 2) {
            loadW8(colH, 8 * (q + 1), w1);
            fma8(w0, hb + 16 * q, m0, m1);
            if (q + 2 < 64) loadW8(colH, 8 * (q + 2), w0);
            else            loadW8(colX, 0, w0);          // next step's xh
            fma8(w1, hb + 16 * (q + 1), m0, m1);
        }

        // ---- h' = tanh(a+m), write state ----
#pragma unroll
        for (int cc = 0; cc < 4; ++cc) {
            const float h0 = eigen_tanhf_fma(a0[cc] + m0[cc]);
            const float h1 = eigen_tanhf_fma(a1[cc] + m1[cc]);
            *(float2*)&hti[nxt][bgp][c0 + cc][0] = make_float2(h0, h1);
        }
        if (morex)
            *(float2*)&xti[nxt][bgp][cg][0] = make_float2(xp0, xp1);
        __syncthreads();
    }

    // ---- head: each thread -> 2 outputs (batch 2bgp,2bgp+1; class cg) ----
    // final h in buffer 0 (SEQ even); ascending-i f64 chain, same as R9.
    {
        const float* hf = &hti[0][bgp][0][0];
        double acc0 = 0.0, acc1 = 0.0;
        for (int i = 0; i < HIDDEN; ++i) {
            const double w = (double)W_hy[(size_t)i * CLASSES + cg];
            acc0 += (double)hf[2 * i]     * w;
            acc1 += (double)hf[2 * i + 1] * w;
        }
        const double by = (double)b_y[cg];
        out[(size_t)(BPW * g + 2 * bgp)     * CLASSES + cg] = (float)(acc0 + by);
        out[(size_t)(BPW * g + 2 * bgp + 1) * CLASSES + cg] = (float)(acc1 + by);
    }
}

extern "C" void kernel_launch(void* const* d_in, const int* in_sizes, int n_in,
                              void* d_out, int out_size, void* d_ws, size_t ws_size,
                              hipStream_t stream)
{
    const float *x, *W_hh, *W_xh, *W_hy, *b_h, *b_y;
    if (in_sizes[0] == BATCH * SEQ * IN_DIM) {
        x    = (const float*)d_in[0];
        W_hh = (const float*)d_in[1];
        W_xh = (const float*)d_in[2];
        W_hy = (const float*)d_in[3];
        b_h  = (const float*)d_in[4];
        b_y  = (const float*)d_in[5];
    } else {
        W_hh = (const float*)d_in[0];
        W_hy = (const float*)d_in[1];
        W_xh = (const float*)d_in[2];
        b_h  = (const float*)d_in[3];
        b_y  = (const float*)d_in[4];
        x    = (const float*)d_in[5];
    }
    float* out = (float*)d_out;
    (void)n_in; (void)out_size; (void)d_ws; (void)ws_size;

    rnn_fast<<<NWG, 512, 0, stream>>>(x, W_hh, W_xh, W_hy, b_h, b_y, out);
}

// Round 3
// 50351.559 us; speedup vs baseline: 2.5645x; 2.5645x over previous
//
#include <hip/hip_runtime.h>
#include <stdint.h>

// VanillaRNN — Round 12: R9 structure, spill ACTUALLY removed.
//
// R9 (50.3 ms, best): WRITE_SIZE=15.76 GB despite only 128 KB of program
// writes -> ~235 B/thread/step of SCRATCH SPILL round-trips. Cause:
// __launch_bounds__(512) with no min-waves arg -> compiler capped at 128
// VGPR, but the hoisted live set (16 next-group W + 8 float4 temps + accs +
// 16 strided 64-bit addrs) exceeds it. Spill traffic (~30 MB/step through
// L2) also thrashed W out of L2 (the 17% miss / 27 GB FETCH).
// R10 (84 ms): global_load_lds staging tripled traffic. Reverted.
// R11 (129 ms): 32-WG reshape, zero spill + zero HBM (FETCH 88 MB total!)
// but latency-exposed at 3% occupancy. Reverted. Its lesson: W IS fully
// L2-residentable; the memory system is fine once spill stops thrashing it.
//
// R12 = R9 byte-identical except __launch_bounds__(512, 2): 2 waves/SIMD
// (exactly our 8-wave/CU residency) -> 256 VGPR budget -> no spill.
//
// Golden universe unchanged (decoded R4-R6): pure f32;
//   xh = chain_{k=0..127} fmaf(x[k], W_xh[k][j]); xh += b_h[j]
//   m  = chain_{i=0..511} fmaf(h[i], W_hh[i][j])   (single ascending chain)
//   h' = eigen_tanhf_fma(xh + m)                    (XLA/Eigen rational, FMA)
// Chain order frozen (chaos, per-step gain ~3.3).

#define BATCH   256
#define SEQ     1024
#define IN_DIM  128
#define HIDDEN  512
#define CLASSES 128
#define NWG     (BATCH / 2)   // 128

// ---- Eigen/XLA rational tanh f32, FMA variant — verbatim R5 ----
__device__ __forceinline__ float eigen_tanhf_fma(float ax) {
#pragma clang fp contract(off)
    const float pc = 7.99881172180175781f, mc = -7.99881172180175781f;
    float x = fmaxf(fminf(ax, pc), mc);
    float x2 = x * x;
    float p = __builtin_fmaf(x2, -2.76076847742355e-16f, 2.00018790482477e-13f);
    p = __builtin_fmaf(x2, p, -8.60467152213735e-11f);
    p = __builtin_fmaf(x2, p, 5.12229709037114e-08f);
    p = __builtin_fmaf(x2, p, 1.48572235717979e-05f);
    p = __builtin_fmaf(x2, p, 6.37261928875436e-04f);
    p = __builtin_fmaf(x2, p, 4.89352455891786e-03f);
    p = x * p;
    float q = __builtin_fmaf(x2, 1.19825839466702e-06f, 1.18534705686654e-04f);
    q = __builtin_fmaf(x2, q, 2.26843463243900e-03f);
    q = __builtin_fmaf(x2, q, 4.89352518554385e-03f);
    float r = p / q;
    return (fabsf(ax) < 0.0004f) ? ax : r;
}

__global__ __launch_bounds__(HIDDEN, 2)
void rnn_fast(const float* __restrict__ x,
              const float* __restrict__ W_hh,
              const float* __restrict__ W_xh,
              const float* __restrict__ W_hy,
              const float* __restrict__ b_h,
              const float* __restrict__ b_y,
              float* __restrict__ out)
{
    // batch-interleaved double-buffered state: [buf][row][batch]
    __shared__ alignas(16) float hti[2][HIDDEN][2];   // 8 KB
    __shared__ alignas(16) float xti[2][IN_DIM][2];   // 2 KB

    const int j = threadIdx.x;   // hidden column
    const int g = blockIdx.x;

    const float bh = b_h[j];
    const float* __restrict__ pX = W_xh + j;  // lane's column in W_xh
    const float* __restrict__ pH = W_hh + j;  // lane's column in W_hh

    const float* xb0 = x + (size_t)(2 * g) * SEQ * IN_DIM;
    const float* xb1 = xb0 + (size_t)SEQ * IN_DIM;

    hti[0][j][0] = 0.0f;
    hti[0][j][1] = 0.0f;
    if (j < 2 * IN_DIM) {
        const int b = j >> 7, k = j & (IN_DIM - 1);
        xti[0][k][b] = (b ? xb1 : xb0)[k];
    }
    __syncthreads();

    for (int t = 0; t < SEQ; ++t) {
        const int cur = t & 1, nxt = cur ^ 1;
        float a0, a1, m0, m1;
        {
#pragma clang fp contract(off)
            // ---- xh chain: 8 groups of 16 rows ----
            a0 = 0.0f; a1 = 0.0f;
            for (int i0 = 0; i0 < IN_DIM; i0 += 16) {
                float w00 = pX[(size_t)(i0 +  0) * HIDDEN];
                float w01 = pX[(size_t)(i0 +  1) * HIDDEN];
                float w02 = pX[(size_t)(i0 +  2) * HIDDEN];
                float w03 = pX[(size_t)(i0 +  3) * HIDDEN];
                float w04 = pX[(size_t)(i0 +  4) * HIDDEN];
                float w05 = pX[(size_t)(i0 +  5) * HIDDEN];
                float w06 = pX[(size_t)(i0 +  6) * HIDDEN];
                float w07 = pX[(size_t)(i0 +  7) * HIDDEN];
                float w08 = pX[(size_t)(i0 +  8) * HIDDEN];
                float w09 = pX[(size_t)(i0 +  9) * HIDDEN];
                float w10 = pX[(size_t)(i0 + 10) * HIDDEN];
                float w11 = pX[(size_t)(i0 + 11) * HIDDEN];
                float w12 = pX[(size_t)(i0 + 12) * HIDDEN];
                float w13 = pX[(size_t)(i0 + 13) * HIDDEN];
                float w14 = pX[(size_t)(i0 + 14) * HIDDEN];
                float w15 = pX[(size_t)(i0 + 15) * HIDDEN];
                const float4 v0 = *(const float4*)&xti[cur][i0 +  0][0];
                const float4 v1 = *(const float4*)&xti[cur][i0 +  2][0];
                const float4 v2 = *(const float4*)&xti[cur][i0 +  4][0];
                const float4 v3 = *(const float4*)&xti[cur][i0 +  6][0];
                const float4 v4 = *(const float4*)&xti[cur][i0 +  8][0];
                const float4 v5 = *(const float4*)&xti[cur][i0 + 10][0];
                const float4 v6 = *(const float4*)&xti[cur][i0 + 12][0];
                const float4 v7 = *(const float4*)&xti[cur][i0 + 14][0];
                a0 = __builtin_fmaf(v0.x, w00, a0); a1 = __builtin_fmaf(v0.y, w00, a1);
                a0 = __builtin_fmaf(v0.z, w01, a0); a1 = __builtin_fmaf(v0.w, w01, a1);
                a0 = __builtin_fmaf(v1.x, w02, a0); a1 = __builtin_fmaf(v1.y, w02, a1);
                a0 = __builtin_fmaf(v1.z, w03, a0); a1 = __builtin_fmaf(v1.w, w03, a1);
                a0 = __builtin_fmaf(v2.x, w04, a0); a1 = __builtin_fmaf(v2.y, w04, a1);
                a0 = __builtin_fmaf(v2.z, w05, a0); a1 = __builtin_fmaf(v2.w, w05, a1);
                a0 = __builtin_fmaf(v3.x, w06, a0); a1 = __builtin_fmaf(v3.y, w06, a1);
                a0 = __builtin_fmaf(v3.z, w07, a0); a1 = __builtin_fmaf(v3.w, w07, a1);
                a0 = __builtin_fmaf(v4.x, w08, a0); a1 = __builtin_fmaf(v4.y, w08, a1);
                a0 = __builtin_fmaf(v4.z, w09, a0); a1 = __builtin_fmaf(v4.w, w09, a1);
                a0 = __builtin_fmaf(v5.x, w10, a0); a1 = __builtin_fmaf(v5.y, w10, a1);
                a0 = __builtin_fmaf(v5.z, w11, a0); a1 = __builtin_fmaf(v5.w, w11, a1);
                a0 = __builtin_fmaf(v6.x, w12, a0); a1 = __builtin_fmaf(v6.y, w12, a1);
                a0 = __builtin_fmaf(v6.z, w13, a0); a1 = __builtin_fmaf(v6.w, w13, a1);
                a0 = __builtin_fmaf(v7.x, w14, a0); a1 = __builtin_fmaf(v7.y, w14, a1);
                a0 = __builtin_fmaf(v7.z, w15, a0); a1 = __builtin_fmaf(v7.w, w15, a1);
            }
            a0 = a0 + bh;
            a1 = a1 + bh;

            // ---- hh chain: 32 groups of 16 rows ----
            m0 = 0.0f; m1 = 0.0f;
            for (int i0 = 0; i0 < HIDDEN; i0 += 16) {
                float w00 = pH[(size_t)(i0 +  0) * HIDDEN];
                float w01 = pH[(size_t)(i0 +  1) * HIDDEN];
                float w02 = pH[(size_t)(i0 +  2) * HIDDEN];
                float w03 = pH[(size_t)(i0 +  3) * HIDDEN];
                float w04 = pH[(size_t)(i0 +  4) * HIDDEN];
                float w05 = pH[(size_t)(i0 +  5) * HIDDEN];
                float w06 = pH[(size_t)(i0 +  6) * HIDDEN];
                float w07 = pH[(size_t)(i0 +  7) * HIDDEN];
                float w08 = pH[(size_t)(i0 +  8) * HIDDEN];
                float w09 = pH[(size_t)(i0 +  9) * HIDDEN];
                float w10 = pH[(size_t)(i0 + 10) * HIDDEN];
                float w11 = pH[(size_t)(i0 + 11) * HIDDEN];
                float w12 = pH[(size_t)(i0 + 12) * HIDDEN];
                float w13 = pH[(size_t)(i0 + 13) * HIDDEN];
                float w14 = pH[(size_t)(i0 + 15) * HIDDEN - HIDDEN]; // i0+14
                float w15 = pH[(size_t)(i0 + 15) * HIDDEN];
                const float4 v0 = *(const float4*)&hti[cur][i0 +  0][0];
                const float4 v1 = *(const float4*)&hti[cur][i0 +  2][0];
                const float4 v2 = *(const float4*)&hti[cur][i0 +  4][0];
                const float4 v3 = *(const float4*)&hti[cur][i0 +  6][0];
                const float4 v4 = *(const float4*)&hti[cur][i0 +  8][0];
                const float4 v5 = *(const float4*)&hti[cur][i0 + 10][0];
                const float4 v6 = *(const float4*)&hti[cur][i0 + 12][0];
                const float4 v7 = *(const float4*)&hti[cur][i0 + 14][0];
                m0 = __builtin_fmaf(v0.x, w00, m0); m1 = __builtin_fmaf(v0.y, w00, m1);
                m0 = __builtin_fmaf(v0.z, w01, m0); m1 = __builtin_fmaf(v0.w, w01, m1);
                m0 = __builtin_fmaf(v1.x, w02, m0); m1 = __builtin_fmaf(v1.y, w02, m1);
                m0 = __builtin_fmaf(v1.z, w03, m0); m1 = __builtin_fmaf(v1.w, w03, m1);
                m0 = __builtin_fmaf(v2.x, w04, m0); m1 = __builtin_fmaf(v2.y, w04, m1);
                m0 = __builtin_fmaf(v2.z, w05, m0); m1 = __builtin_fmaf(v2.w, w05, m1);
                m0 = __builtin_fmaf(v3.x, w06, m0); m1 = __builtin_fmaf(v3.y, w06, m1);
                m0 = __builtin_fmaf(v3.z, w07, m0); m1 = __builtin_fmaf(v3.w, w07, m1);
                m0 = __builtin_fmaf(v4.x, w08, m0); m1 = __builtin_fmaf(v4.y, w08, m1);
                m0 = __builtin_fmaf(v4.z, w09, m0); m1 = __builtin_fmaf(v4.w, w09, m1);
                m0 = __builtin_fmaf(v5.x, w10, m0); m1 = __builtin_fmaf(v5.y, w10, m1);
                m0 = __builtin_fmaf(v5.z, w11, m0); m1 = __builtin_fmaf(v5.w, w11, m1);
                m0 = __builtin_fmaf(v6.x, w12, m0); m1 = __builtin_fmaf(v6.y, w12, m1);
                m0 = __builtin_fmaf(v6.z, w13, m0); m1 = __builtin_fmaf(v6.w, w13, m1);
                m0 = __builtin_fmaf(v7.x, w14, m0); m1 = __builtin_fmaf(v7.y, w14, m1);
                m0 = __builtin_fmaf(v7.z, w15, m0); m1 = __builtin_fmaf(v7.w, w15, m1);
            }
        }

        const float h0 = eigen_tanhf_fma(a0 + m0);
        const float h1 = eigen_tanhf_fma(a1 + m1);

        if (t + 1 < SEQ && j < 2 * IN_DIM) {
            const int b = j >> 7, k = j & (IN_DIM - 1);
            xti[nxt][k][b] = (b ? xb1 : xb0)[(t + 1) * IN_DIM + k];
        }
        *(float2*)&hti[nxt][j][0] = make_float2(h0, h1);
        __syncthreads();
    }

    // ---- head: out[2g+b, c] = h_final[b,:] @ W_hy[:,c] + b_y[c] ----
    // final h in buffer 0 (SEQ even); f64 acc, same as R5-R9 (absmax 0.125).
    if (j < 2 * CLASSES) {
        const int b = j >> 7;
        const int c = j & (CLASSES - 1);
        double acc = 0.0;
        for (int i = 0; i < HIDDEN; ++i) {
            acc += (double)hti[0][i][b] * (double)W_hy[i * CLASSES + c];
        }
        acc += (double)b_y[c];
        out[(size_t)(2 * g + b) * CLASSES + c] = (float)acc;
    }
}

extern "C" void kernel_launch(void* const* d_in, const int* in_sizes, int n_in,
                              void* d_out, int out_size, void* d_ws, size_t ws_size,
                              hipStream_t stream)
{
    const float *x, *W_hh, *W_xh, *W_hy, *b_h, *b_y;
    if (in_sizes[0] == BATCH * SEQ * IN_DIM) {
        x    = (const float*)d_in[0];
        W_hh = (const float*)d_in[1];
        W_xh = (const float*)d_in[2];
        W_hy = (const float*)d_in[3];
        b_h  = (const float*)d_in[4];
        b_y  = (const float*)d_in[5];
    } else {
        W_hh = (const float*)d_in[0];
        W_hy = (const float*)d_in[1];
        W_xh = (const float*)d_in[2];
        b_h  = (const float*)d_in[3];
        b_y  = (const float*)d_in[4];
        x    = (const float*)d_in[5];
    }
    float* out = (float*)d_out;
    (void)n_in; (void)out_size; (void)d_ws; (void)ws_size;

    rnn_fast<<<NWG, HIDDEN, 0, stream>>>(x, W_hh, W_xh, W_hy, b_h, b_y, out);
}